// Round 1
// baseline (318.886 us; speedup 1.0000x reference)
//
#include <hip/hip_runtime.h>

#define BATCH 131072
#define UNITS 512
#define DIM   64
#define BM    128

typedef __attribute__((ext_vector_type(8))) short  short8;
typedef __attribute__((ext_vector_type(4))) float  floatx4;

static __device__ __forceinline__ unsigned short f32_to_bf16(float f) {
    union { float f; unsigned int u; } c; c.f = f;
    unsigned int u = c.u;
    unsigned int r = u + 0x7fffu + ((u >> 16) & 1u);   // round-nearest-even
    return (unsigned short)(r >> 16);
}

// Convert w [512][64] fp32 -> bf16, and per-row sum of squares.
__global__ __launch_bounds__(256) void prep_w_kernel(
    const float* __restrict__ w,
    unsigned short* __restrict__ wb,
    float* __restrict__ wsq)
{
    const int u = blockIdx.x * 4 + (threadIdx.x >> 6);   // one wave per w-row
    const int d = threadIdx.x & 63;
    float v = w[u * DIM + d];
    wb[u * DIM + d] = f32_to_bf16(v);
    float s = v * v;
    #pragma unroll
    for (int o = 32; o > 0; o >>= 1) s += __shfl_xor(s, o);
    if (d == 0) wsq[u] = s;
}

// dist[b,u] = ||x_b||^2 + ||w_u||^2 - 2 * x_b . w_u
__global__ __launch_bounds__(256) void dist_kernel(
    const float* __restrict__ x,
    const unsigned short* __restrict__ wb,
    const float* __restrict__ wsq,
    float* __restrict__ out)
{
    __shared__ __align__(16) unsigned short xb[BM][DIM];  // bf16 x tile, 16 KB
    __shared__ float xsq[BM];

    const int tid  = threadIdx.x;
    const int row0 = blockIdx.x * BM;

    // ---- stage x tile: fp32 -> bf16 into LDS, fused row sum-of-squares ----
    // 256 threads = 64 rows x 4 quarter-rows per iteration; fully coalesced.
    #pragma unroll
    for (int half = 0; half < BM / 64; ++half) {
        const int r = half * 64 + (tid >> 2);
        const int q = tid & 3;
        const float4* src = (const float4*)(x + (size_t)(row0 + r) * DIM + q * 16);
        float v[16];
        *(float4*)&v[0]  = src[0];
        *(float4*)&v[4]  = src[1];
        *(float4*)&v[8]  = src[2];
        *(float4*)&v[12] = src[3];
        float s = 0.f;
        unsigned short p[16];
        #pragma unroll
        for (int i = 0; i < 16; ++i) { s += v[i] * v[i]; p[i] = f32_to_bf16(v[i]); }
        uint4* dst = (uint4*)&xb[r][q * 16];
        dst[0] = *(uint4*)&p[0];
        dst[1] = *(uint4*)&p[8];
        s += __shfl_xor(s, 1);
        s += __shfl_xor(s, 2);
        if (q == 0) xsq[r] = s;
    }
    __syncthreads();

    // ---- MFMA phase: each wave computes 32 rows x 512 cols ----
    const int wave = tid >> 6;
    const int lane = tid & 63;
    const int l15  = lane & 15;
    const int quad = lane >> 4;
    const int mrow = wave * 32;

    // a-frags: A[m=lane&15][k=quad*8+j], two m-frags, two k-halves (K=64)
    const short8* arow0 = (const short8*)&xb[mrow + l15][0];
    const short8* arow1 = (const short8*)&xb[mrow + 16 + l15][0];
    const short8 a00 = arow0[quad];
    const short8 a01 = arow0[quad + 4];
    const short8 a10 = arow1[quad];
    const short8 a11 = arow1[quad + 4];

    float xs0[4], xs1[4];
    #pragma unroll
    for (int i = 0; i < 4; ++i) {
        xs0[i] = xsq[mrow + quad * 4 + i];
        xs1[i] = xsq[mrow + 16 + quad * 4 + i];
    }

    const short8* wv = (const short8*)wb;   // w rows as groups of 8 bf16

    for (int ut = 0; ut < UNITS / 16; ++ut) {
        const int ubase = ut * 16;
        // b-frag: B[k=quad*8+j][n=lane&15] = w[n][k] -> contiguous 16B of w row
        const short8 b0 = wv[(ubase + l15) * 8 + quad];
        const short8 b1 = wv[(ubase + l15) * 8 + quad + 4];
        floatx4 acc0 = {0.f, 0.f, 0.f, 0.f};
        floatx4 acc1 = {0.f, 0.f, 0.f, 0.f};
        acc0 = __builtin_amdgcn_mfma_f32_16x16x32_bf16(a00, b0, acc0, 0, 0, 0);
        acc0 = __builtin_amdgcn_mfma_f32_16x16x32_bf16(a01, b1, acc0, 0, 0, 0);
        acc1 = __builtin_amdgcn_mfma_f32_16x16x32_bf16(a10, b0, acc1, 0, 0, 0);
        acc1 = __builtin_amdgcn_mfma_f32_16x16x32_bf16(a11, b1, acc1, 0, 0, 0);

        const float wq = wsq[ubase + l15];
        const int col = ubase + l15;
        #pragma unroll
        for (int i = 0; i < 4; ++i) {
            // C/D layout: col = lane&15, row = quad*4 + reg
            const size_t r0i = (size_t)(row0 + mrow + quad * 4 + i) * UNITS + col;
            const size_t r1i = (size_t)(row0 + mrow + 16 + quad * 4 + i) * UNITS + col;
            __builtin_nontemporal_store(xs0[i] + wq - 2.0f * acc0[i], &out[r0i]);
            __builtin_nontemporal_store(xs1[i] + wq - 2.0f * acc1[i], &out[r1i]);
        }
    }
}

extern "C" void kernel_launch(void* const* d_in, const int* in_sizes, int n_in,
                              void* d_out, int out_size, void* d_ws, size_t ws_size,
                              hipStream_t stream) {
    const float* x = (const float*)d_in[0];
    const float* w = (const float*)d_in[1];
    float* out = (float*)d_out;

    unsigned short* wb  = (unsigned short*)d_ws;                       // 512*64*2 = 64 KB
    float*          wsq = (float*)((char*)d_ws + UNITS * DIM * 2);     // 2 KB

    prep_w_kernel<<<UNITS / 4, 256, 0, stream>>>(w, wb, wsq);
    dist_kernel<<<BATCH / BM, 256, 0, stream>>>(x, wb, wsq, out);
}

// Round 3
// 293.835 us; speedup vs baseline: 1.0853x; 1.0853x over previous
//
#include <hip/hip_runtime.h>

#define BATCH 131072
#define UNITS 512
#define DIM   64
#define BM    128
#define STRIDE 68   // floats; 68%32==4 -> 4-aligned bank groups, 16B-aligned rows

typedef __attribute__((ext_vector_type(8))) short  short8;
typedef __attribute__((ext_vector_type(4))) float  floatx4;

static __device__ __forceinline__ unsigned short f32_to_bf16(float f) {
    union { float f; unsigned int u; } c; c.f = f;
    unsigned int u = c.u;
    unsigned int r = u + 0x7fffu + ((u >> 16) & 1u);   // round-nearest-even
    return (unsigned short)(r >> 16);
}

// Convert w [512][64] fp32 -> bf16, and per-row sum of squares.
__global__ __launch_bounds__(256) void prep_w_kernel(
    const float* __restrict__ w,
    unsigned short* __restrict__ wb,
    float* __restrict__ wsq)
{
    const int u = blockIdx.x * 4 + (threadIdx.x >> 6);   // one wave per w-row
    const int d = threadIdx.x & 63;
    float v = w[u * DIM + d];
    wb[u * DIM + d] = f32_to_bf16(v);
    float s = v * v;
    #pragma unroll
    for (int o = 32; o > 0; o >>= 1) s += __shfl_xor(s, o);
    if (d == 0) wsq[u] = s;
}

// dist[b,u] = ||x_b||^2 + ||w_u||^2 - 2 * x_b . w_u
// 16x16x32 MFMA (HW-verified layouts, same as the passing R1 kernel).
// Epilogue: wave-private LDS transpose -> float4 nontemporal stores,
// each store instruction = 4 x 256 B line-aligned segments.
__global__ __launch_bounds__(256) void dist_kernel(
    const float* __restrict__ x,
    const unsigned short* __restrict__ wb,
    const float* __restrict__ wsq,
    float* __restrict__ out)
{
    __shared__ __align__(16) unsigned short xb[BM][DIM];   // 16 KB
    __shared__ float xsq[BM];
    __shared__ float wsq_s[UNITS];
    __shared__ __align__(16) float st[4][16][STRIDE];      // 17.4 KB, per-wave chunks

    const int tid  = threadIdx.x;
    const int row0 = blockIdx.x * BM;

    // stage wsq into LDS
    wsq_s[tid]       = wsq[tid];
    wsq_s[tid + 256] = wsq[tid + 256];

    // ---- stage x tile: fp32 -> bf16 into LDS, fused row sum-of-squares ----
    #pragma unroll
    for (int half = 0; half < BM / 64; ++half) {
        const int r = half * 64 + (tid >> 2);
        const int q = tid & 3;
        const float4* src = (const float4*)(x + (size_t)(row0 + r) * DIM + q * 16);
        float v[16];
        *(float4*)&v[0]  = src[0];
        *(float4*)&v[4]  = src[1];
        *(float4*)&v[8]  = src[2];
        *(float4*)&v[12] = src[3];
        float s = 0.f;
        unsigned short p[16];
        #pragma unroll
        for (int i = 0; i < 16; ++i) { s += v[i] * v[i]; p[i] = f32_to_bf16(v[i]); }
        uint4* dst = (uint4*)&xb[r][q * 16];
        dst[0] = *(uint4*)&p[0];
        dst[1] = *(uint4*)&p[8];
        s += __shfl_xor(s, 1);
        s += __shfl_xor(s, 2);
        if (q == 0) xsq[r] = s;
    }
    __syncthreads();

    const int wave = tid >> 6;
    const int lane = tid & 63;
    const int l15  = lane & 15;
    const int quad = lane >> 4;
    const int mrow = wave * 32;

    // A-frags (verified): A[m = lane&15][k = quad*8 + j], two k-halves of 32
    short8 a[2][2];
    float  xs[2][4];
    #pragma unroll
    for (int mf = 0; mf < 2; ++mf) {
        const short8* ar = (const short8*)&xb[mrow + mf * 16 + l15][0];
        a[mf][0] = ar[quad];
        a[mf][1] = ar[quad + 4];
        #pragma unroll
        for (int i = 0; i < 4; ++i)
            xs[mf][i] = xsq[mrow + mf * 16 + quad * 4 + i];
    }

    const short8* wv  = (const short8*)wb;   // w rows as groups of 8 bf16
    float*        stw = &st[wave][0][0];     // wave-private stage

    for (int gu = 0; gu < 8; ++gu) {         // 8 groups of 64 cols
        const int colb = gu * 64;

        // B-frags for 4 col-tiles x 2 k-halves (verified layout from R1)
        short8 b[4][2];
        float  wq[4];
        #pragma unroll
        for (int t = 0; t < 4; ++t) {
            const short8* bp = wv + (size_t)(colb + t * 16 + l15) * 8;
            b[t][0] = bp[quad];
            b[t][1] = bp[quad + 4];
            wq[t]   = wsq_s[colb + t * 16 + l15];
        }

        #pragma unroll
        for (int mf = 0; mf < 2; ++mf) {
            floatx4 acc[4];
            #pragma unroll
            for (int t = 0; t < 4; ++t) {
                acc[t] = floatx4{0.f, 0.f, 0.f, 0.f};
                acc[t] = __builtin_amdgcn_mfma_f32_16x16x32_bf16(a[mf][0], b[t][0], acc[t], 0, 0, 0);
                acc[t] = __builtin_amdgcn_mfma_f32_16x16x32_bf16(a[mf][1], b[t][1], acc[t], 0, 0, 0);
            }

            // stage 16 rows x 64 cols to wave-private LDS
            // C/D layout (verified): row = quad*4 + i, col = t*16 + l15
            #pragma unroll
            for (int t = 0; t < 4; ++t)
                #pragma unroll
                for (int i = 0; i < 4; ++i)
                    stw[(quad * 4 + i) * STRIDE + t * 16 + l15] =
                        xs[mf][i] + wq[t] - 2.0f * acc[t][i];

            // readback + coalesced nt stores (DS ops in-order within a wave:
            // no barrier needed for wave-private write->read)
            #pragma unroll
            for (int j = 0; j < 4; ++j) {
                const int r = quad + 4 * j;    // 16 rows over j
                const floatx4 v = *(const floatx4*)&stw[r * STRIDE + l15 * 4];
                float* dst = out + (size_t)(row0 + mrow + mf * 16 + r) * UNITS
                                 + colb + l15 * 4;
                __builtin_nontemporal_store(v, (floatx4*)dst);
            }
        }
    }
}

extern "C" void kernel_launch(void* const* d_in, const int* in_sizes, int n_in,
                              void* d_out, int out_size, void* d_ws, size_t ws_size,
                              hipStream_t stream) {
    const float* x = (const float*)d_in[0];
    const float* w = (const float*)d_in[1];
    float* out = (float*)d_out;

    unsigned short* wb  = (unsigned short*)d_ws;                       // 64 KB
    float*          wsq = (float*)((char*)d_ws + UNITS * DIM * 2);     // 2 KB

    prep_w_kernel<<<UNITS / 4, 256, 0, stream>>>(w, wb, wsq);
    dist_kernel<<<BATCH / BM, 256, 0, stream>>>(x, wb, wsq, out);
}